// Round 3
// baseline (2118.052 us; speedup 1.0000x reference)
//
#include <hip/hip_runtime.h>
#include <hip/hip_bf16.h>

#define N_A 100000
#define N_B 100000
#define E_AA 400000
#define E_AB 800000
#define E_BA 800000

// ---------------------------------------------------------------------------
// Layer-0 closed form: hA starts as tile(emb_A), so every edge of a type
// carries the same message vector. hA1[i] = relu(cA + deg_aa[i]*u + deg_ba[i]*v)
// This kernel computes the five 64-vectors: sv = [cA, u_aa, v_ba, cB, w_ab]
// ---------------------------------------------------------------------------
__global__ void precompute_vecs(const float* __restrict__ emb_A, const float* __restrict__ emb_B,
    const float* __restrict__ W_aa, const float* __restrict__ b_aa,
    const float* __restrict__ W_ab, const float* __restrict__ b_ab,
    const float* __restrict__ W_ba, const float* __restrict__ b_ba,
    const float* __restrict__ Wn_A, const float* __restrict__ bn_A,
    const float* __restrict__ Wn_B, const float* __restrict__ bn_B,
    float* __restrict__ sv)
{
    __shared__ float ea[64], eb[64], maa[64], mab[64], mba[64];
    int j = threadIdx.x;
    ea[j] = emb_A[j];
    eb[j] = emb_B[j];
    __syncthreads();
    float s_aa = b_aa[j], s_ab = b_ab[j], s_ba = b_ba[j];
    for (int k = 0; k < 64; ++k) {
        s_aa += ea[k] * W_aa[k*64 + j];
        s_ab += ea[k] * W_ab[k*64 + j];
        s_ba += eb[k] * W_ba[k*64 + j];
    }
    maa[j] = fmaxf(s_aa, 0.f);
    mab[j] = fmaxf(s_ab, 0.f);
    mba[j] = fmaxf(s_ba, 0.f);
    __syncthreads();
    float cA = bn_A[j], u = 0.f, v = 0.f, cB = bn_B[j], w = 0.f;
    for (int k = 0; k < 64; ++k) {
        cA += ea[k]  * Wn_A[k*64 + j];
        u  += maa[k] * Wn_A[(64+k)*64 + j];
        v  += mba[k] * Wn_A[(128+k)*64 + j];
        cB += eb[k]  * Wn_B[k*64 + j];
        w  += mab[k] * Wn_B[(64+k)*64 + j];
    }
    sv[j] = cA; sv[64+j] = u; sv[128+j] = v; sv[192+j] = cB; sv[256+j] = w;
}

__global__ void deg_hist(const int* __restrict__ dst, int n, int* __restrict__ deg)
{
    int i = blockIdx.x * blockDim.x + threadIdx.x;
    if (i < n) atomicAdd(deg + dst[i], 1);
}

__global__ void layer0_nodes(const int* __restrict__ deg_aa, const int* __restrict__ deg_ba,
                             const int* __restrict__ deg_ab, const float* __restrict__ sv,
                             float* __restrict__ hA1, float* __restrict__ hB1)
{
    __shared__ float s[320];
    for (int t = threadIdx.x; t < 320; t += blockDim.x)   // strided: block=256 < 320
        s[t] = sv[t];
    __syncthreads();
    int gid = blockIdx.x * blockDim.x + threadIdx.x;
    int total = (N_A + N_B) * 64;
    for (int idx = gid; idx < total; idx += gridDim.x * blockDim.x) {
        int i = idx >> 6, j = idx & 63;
        if (i < N_A) {
            float da = (float)deg_aa[i];
            float db = (float)deg_ba[i];
            hA1[idx] = fmaxf(s[j] + da * s[64+j] + db * s[128+j], 0.f);
        } else {
            int b = i - N_A;
            float dd = (float)deg_ab[b];
            hB1[(size_t)b*64 + j] = fmaxf(s[192+j] + dd * s[256+j], 0.f);
        }
    }
}

// ---------------------------------------------------------------------------
// g = relu(h @ W + b), optionally two weight sets sharing one read of h.
// Block = 256 threads, 16 rows/block, thread computes 4 cols of one row.
// ---------------------------------------------------------------------------
template<int NW>
__global__ __launch_bounds__(256) void node_transform(
    const float* __restrict__ h,
    const float* __restrict__ W0, const float* __restrict__ b0,
    const float* __restrict__ W1, const float* __restrict__ b1,
    float* __restrict__ g0, float* __restrict__ g1)
{
    __shared__ float Ws[NW * 4096];
    __shared__ float hs[16][65];   // +1 pad: rows stride 65 -> no bank conflict
    int tid = threadIdx.x;
    for (int t = tid; t < NW * 4096; t += 256)
        Ws[t] = (t < 4096) ? W0[t] : W1[t - 4096];
    size_t rbase = (size_t)blockIdx.x * 16;
    for (int t = tid; t < 1024; t += 256)
        hs[t >> 6][t & 63] = h[rbase * 64 + t];
    __syncthreads();
    int r  = tid >> 4;
    int c0 = (tid & 15) * 4;
    float a00 = b0[c0], a01 = b0[c0+1], a02 = b0[c0+2], a03 = b0[c0+3];
    float a10 = 0.f, a11 = 0.f, a12 = 0.f, a13 = 0.f;
    if constexpr (NW == 2) { a10 = b1[c0]; a11 = b1[c0+1]; a12 = b1[c0+2]; a13 = b1[c0+3]; }
    for (int k = 0; k < 64; ++k) {
        float hv = hs[r][k];
        float4 w0 = *(const float4*)&Ws[k*64 + c0];
        a00 += hv*w0.x; a01 += hv*w0.y; a02 += hv*w0.z; a03 += hv*w0.w;
        if constexpr (NW == 2) {
            float4 w1 = *(const float4*)&Ws[4096 + k*64 + c0];
            a10 += hv*w1.x; a11 += hv*w1.y; a12 += hv*w1.z; a13 += hv*w1.w;
        }
    }
    size_t o = (rbase + r) * 64 + c0;
    *(float4*)(g0 + o) = make_float4(fmaxf(a00,0.f), fmaxf(a01,0.f), fmaxf(a02,0.f), fmaxf(a03,0.f));
    if constexpr (NW == 2)
        *(float4*)(g1 + o) = make_float4(fmaxf(a10,0.f), fmaxf(a11,0.f), fmaxf(a12,0.f), fmaxf(a13,0.f));
}

// ---------------------------------------------------------------------------
// r[dst] += g[src]  (16 threads/edge, float4 each, hw f32 atomics)
// ---------------------------------------------------------------------------
__global__ void scatter_add(const int* __restrict__ src, const int* __restrict__ dst, int ne,
                            const float* __restrict__ g, float* r)
{
    int gid = blockIdx.x * blockDim.x + threadIdx.x;
    if (gid >= ne * 16) return;
    int e = gid >> 4, c = gid & 15;
    int s = src[e], d = dst[e];
    float4 v = *(const float4*)(g + (size_t)s * 64 + c * 4);
    float* rp = r + (size_t)d * 64 + c * 4;
    unsafeAtomicAdd(rp + 0, v.x);
    unsafeAtomicAdd(rp + 1, v.y);
    unsafeAtomicAdd(rp + 2, v.z);
    unsafeAtomicAdd(rp + 3, v.w);
}

// ---------------------------------------------------------------------------
// out = relu(concat(srcs) @ Wn + bn). rX may alias out (disjoint rows per
// block; reads complete into LDS before the write). NS = 3 (A) or 2 (B).
// ---------------------------------------------------------------------------
template<int NS>
__global__ __launch_bounds__(256) void node_update(
    const float* __restrict__ h,
    const float* rX,                  // no restrict: may alias out
    const float* __restrict__ rY,
    const float* __restrict__ Wn, const float* __restrict__ bn,
    float* out)
{
    __shared__ float Ws[NS * 4096];
    __shared__ float hs[NS][16][65];
    int tid = threadIdx.x;
    for (int t = tid; t < NS * 4096; t += 256) Ws[t] = Wn[t];
    size_t rbase = (size_t)blockIdx.x * 16;
    for (int t = tid; t < 1024; t += 256) {
        int rr = t >> 6, k = t & 63;
        size_t gi = rbase * 64 + t;
        hs[0][rr][k] = h[gi];
        hs[1][rr][k] = rX[gi];
        if constexpr (NS == 3) hs[2][rr][k] = rY[gi];
    }
    __syncthreads();
    int r  = tid >> 4;
    int c0 = (tid & 15) * 4;
    float a0 = bn[c0], a1 = bn[c0+1], a2 = bn[c0+2], a3 = bn[c0+3];
    for (int s = 0; s < NS; ++s)
        for (int k = 0; k < 64; ++k) {
            float hv = hs[s][r][k];
            float4 w = *(const float4*)&Ws[(s*64 + k)*64 + c0];
            a0 += hv*w.x; a1 += hv*w.y; a2 += hv*w.z; a3 += hv*w.w;
        }
    *(float4*)(out + (rbase + r) * 64 + c0) =
        make_float4(fmaxf(a0,0.f), fmaxf(a1,0.f), fmaxf(a2,0.f), fmaxf(a3,0.f));
}

extern "C" void kernel_launch(void* const* d_in, const int* in_sizes, int n_in,
                              void* d_out, int out_size, void* d_ws, size_t ws_size,
                              hipStream_t stream)
{
    const int*   src_aa = (const int*)d_in[0];
    const int*   dst_aa = (const int*)d_in[1];
    const int*   src_ab = (const int*)d_in[2];
    const int*   dst_ab = (const int*)d_in[3];
    const int*   src_ba = (const int*)d_in[4];
    const int*   dst_ba = (const int*)d_in[5];
    const float* emb_A  = (const float*)d_in[6];
    const float* emb_B  = (const float*)d_in[7];
    const float* W_aa   = (const float*)d_in[8];
    const float* b_aa   = (const float*)d_in[9];
    const float* W_ab   = (const float*)d_in[10];
    const float* b_ab   = (const float*)d_in[11];
    const float* W_ba   = (const float*)d_in[12];
    const float* b_ba   = (const float*)d_in[13];
    const float* Wn_A   = (const float*)d_in[14];
    const float* bn_A   = (const float*)d_in[15];
    const float* Wn_B   = (const float*)d_in[16];
    const float* bn_B   = (const float*)d_in[17];

    // workspace layout (floats): sv[512] | deg_aa | deg_ba | deg_ab | hA1 | hB1 | g0 | g1
    // r_ba overlays g1 (g1 is dead after scatter_ab; re-zeroed mid-stream).
    // total ~104 MiB
    float* ws   = (float*)d_ws;
    float* sv   = ws;
    int*   deg_aa_p = (int*)(ws + 512);
    int*   deg_ba_p = deg_aa_p + N_A;
    int*   deg_ab_p = deg_ba_p + N_A;
    float* hA1  = ws + 512 + 2*N_A + N_B;
    float* hB1  = hA1 + (size_t)N_A * 64;
    float* g0   = hB1 + (size_t)N_B * 64;
    float* g1   = g0  + (size_t)N_A * 64;
    float* r_ba = g1;                        // overlay

    float* outA = (float*)d_out;              // doubles as r_aa accumulator
    float* outB = outA + (size_t)N_A * 64;    // doubles as r_ab accumulator

    hipMemsetAsync(deg_aa_p, 0, (size_t)(2*N_A + N_B) * sizeof(int), stream);
    hipMemsetAsync(d_out, 0, (size_t)out_size * sizeof(float), stream);

    precompute_vecs<<<1, 64, 0, stream>>>(emb_A, emb_B, W_aa, b_aa, W_ab, b_ab,
                                          W_ba, b_ba, Wn_A, bn_A, Wn_B, bn_B, sv);
    deg_hist<<<(E_AA + 255) / 256, 256, 0, stream>>>(dst_aa, E_AA, deg_aa_p);
    deg_hist<<<(E_AB + 255) / 256, 256, 0, stream>>>(dst_ab, E_AB, deg_ab_p);
    deg_hist<<<(E_BA + 255) / 256, 256, 0, stream>>>(dst_ba, E_BA, deg_ba_p);
    layer0_nodes<<<4096, 256, 0, stream>>>(deg_aa_p, deg_ba_p, deg_ab_p, sv, hA1, hB1);

    // layer 1: per-node edge transforms (weights at layer-1 offsets)
    node_transform<2><<<N_A / 16, 256, 0, stream>>>(hA1, W_aa + 4096, b_aa + 64,
                                                    W_ab + 4096, b_ab + 64, g0, g1);
    scatter_add<<<(E_AA * 16 + 255) / 256, 256, 0, stream>>>(src_aa, dst_aa, E_AA, g0, outA);
    scatter_add<<<(E_AB * 16 + 255) / 256, 256, 0, stream>>>(src_ab, dst_ab, E_AB, g1, outB);
    // g1 is now dead -> reuse as r_ba
    hipMemsetAsync(r_ba, 0, (size_t)N_A * 64 * sizeof(float), stream);
    node_transform<1><<<N_B / 16, 256, 0, stream>>>(hB1, W_ba + 4096, b_ba + 64,
                                                    nullptr, nullptr, g0, nullptr);
    scatter_add<<<(E_BA * 16 + 255) / 256, 256, 0, stream>>>(src_ba, dst_ba, E_BA, g0, r_ba);

    // node updates (layer-1 weights); r_aa/r_ab read from d_out then overwritten
    node_update<3><<<N_A / 16, 256, 0, stream>>>(hA1, outA, r_ba, Wn_A + 12288, bn_A + 64, outA);
    node_update<2><<<N_B / 16, 256, 0, stream>>>(hB1, outB, nullptr, Wn_B + 8192, bn_B + 64, outB);
}

// Round 7
// 1422.720 us; speedup vs baseline: 1.4887x; 1.4887x over previous
//
#include <hip/hip_runtime.h>
#include <hip/hip_bf16.h>

#define N_A 100000
#define N_B 100000
#define E_AA 400000
#define E_AB 800000
#define E_BA 800000

// ---------------------------------------------------------------------------
// Layer-0 closed form: hA starts as tile(emb_A), so every edge of a type
// carries the same message vector. hA1[i] = relu(cA + deg_aa[i]*u + deg_ba[i]*v)
// sv = [cA, u_aa, v_ba, cB, w_ab] (five 64-vectors)
// ---------------------------------------------------------------------------
__global__ void precompute_vecs(const float* __restrict__ emb_A, const float* __restrict__ emb_B,
    const float* __restrict__ W_aa, const float* __restrict__ b_aa,
    const float* __restrict__ W_ab, const float* __restrict__ b_ab,
    const float* __restrict__ W_ba, const float* __restrict__ b_ba,
    const float* __restrict__ Wn_A, const float* __restrict__ bn_A,
    const float* __restrict__ Wn_B, const float* __restrict__ bn_B,
    float* __restrict__ sv)
{
    __shared__ float ea[64], eb[64], maa[64], mab[64], mba[64];
    int j = threadIdx.x;
    ea[j] = emb_A[j];
    eb[j] = emb_B[j];
    __syncthreads();
    float s_aa = b_aa[j], s_ab = b_ab[j], s_ba = b_ba[j];
    for (int k = 0; k < 64; ++k) {
        s_aa += ea[k] * W_aa[k*64 + j];
        s_ab += ea[k] * W_ab[k*64 + j];
        s_ba += eb[k] * W_ba[k*64 + j];
    }
    maa[j] = fmaxf(s_aa, 0.f);
    mab[j] = fmaxf(s_ab, 0.f);
    mba[j] = fmaxf(s_ba, 0.f);
    __syncthreads();
    float cA = bn_A[j], u = 0.f, v = 0.f, cB = bn_B[j], w = 0.f;
    for (int k = 0; k < 64; ++k) {
        cA += ea[k]  * Wn_A[k*64 + j];
        u  += maa[k] * Wn_A[(64+k)*64 + j];
        v  += mba[k] * Wn_A[(128+k)*64 + j];
        cB += eb[k]  * Wn_B[k*64 + j];
        w  += mab[k] * Wn_B[(64+k)*64 + j];
    }
    sv[j] = cA; sv[64+j] = u; sv[128+j] = v; sv[192+j] = cB; sv[256+j] = w;
}

__global__ void deg_hist(const int* __restrict__ dst, int n, int* __restrict__ deg)
{
    int i = blockIdx.x * blockDim.x + threadIdx.x;
    if (i < n) atomicAdd(deg + dst[i], 1);
}

// Exclusive prefix sum over n<=100k elements, single block of 1024.
// Writes rp[0..n] and cursor copy cur[0..n-1].
__global__ __launch_bounds__(1024) void exscan(const int* __restrict__ deg, int n,
                                               int* __restrict__ rp, int* __restrict__ cur)
{
    __shared__ int ps[1024];
    int tid = threadIdx.x;
    int chunk = (n + 1023) >> 10;
    int lo = tid * chunk;
    int hi = lo + chunk; if (hi > n) hi = n; if (lo > n) lo = n;
    int s = 0;
    for (int i = lo; i < hi; ++i) s += deg[i];
    ps[tid] = s;
    __syncthreads();
    for (int off = 1; off < 1024; off <<= 1) {       // Hillis-Steele inclusive
        int v = (tid >= off) ? ps[tid - off] : 0;
        __syncthreads();
        ps[tid] += v;
        __syncthreads();
    }
    if (tid == 1023) rp[n] = ps[1023];               // total = E
    int run = (tid ? ps[tid - 1] : 0);
    for (int i = lo; i < hi; ++i) {
        rp[i] = run; cur[i] = run;
        run += deg[i];
    }
}

// counting-sort fill: perm[] = src indices grouped by dst
__global__ void fill_perm(const int* __restrict__ src, const int* __restrict__ dst, int ne,
                          int* __restrict__ cur, int* __restrict__ perm)
{
    int i = blockIdx.x * blockDim.x + threadIdx.x;
    if (i < ne) {
        int p = atomicAdd(cur + dst[i], 1);
        perm[p] = src[i];
    }
}

__global__ void layer0_nodes(const int* __restrict__ deg_aa, const int* __restrict__ deg_ba,
                             const int* __restrict__ deg_ab, const float* __restrict__ sv,
                             float* __restrict__ hA1, float* __restrict__ hB1)
{
    __shared__ float s[320];
    for (int t = threadIdx.x; t < 320; t += blockDim.x)
        s[t] = sv[t];
    __syncthreads();
    int gid = blockIdx.x * blockDim.x + threadIdx.x;
    int total = (N_A + N_B) * 64;
    for (int idx = gid; idx < total; idx += gridDim.x * blockDim.x) {
        int i = idx >> 6, j = idx & 63;
        if (i < N_A) {
            float da = (float)deg_aa[i];
            float db = (float)deg_ba[i];
            hA1[idx] = fmaxf(s[j] + da * s[64+j] + db * s[128+j], 0.f);
        } else {
            int b = i - N_A;
            float dd = (float)deg_ab[b];
            hB1[(size_t)b*64 + j] = fmaxf(s[192+j] + dd * s[256+j], 0.f);
        }
    }
}

// ---------------------------------------------------------------------------
// g = relu(h @ W + b). Block = 256 threads, 16 rows, thread = 4 cols of a row.
// ---------------------------------------------------------------------------
__global__ __launch_bounds__(256) void node_transform(
    const float* __restrict__ h,
    const float* __restrict__ W0, const float* __restrict__ b0,
    float* __restrict__ g0)
{
    __shared__ float Ws[4096];
    __shared__ float hs[16][65];
    int tid = threadIdx.x;
    for (int t = tid; t < 4096; t += 256) Ws[t] = W0[t];
    size_t rbase = (size_t)blockIdx.x * 16;
    for (int t = tid; t < 1024; t += 256)
        hs[t >> 6][t & 63] = h[rbase * 64 + t];
    __syncthreads();
    int r  = tid >> 4;
    int c0 = (tid & 15) * 4;
    float a0 = b0[c0], a1 = b0[c0+1], a2 = b0[c0+2], a3 = b0[c0+3];
    for (int k = 0; k < 64; ++k) {
        float hv = hs[r][k];
        float4 w0 = *(const float4*)&Ws[k*64 + c0];
        a0 += hv*w0.x; a1 += hv*w0.y; a2 += hv*w0.z; a3 += hv*w0.w;
    }
    size_t o = (rbase + r) * 64 + c0;
    *(float4*)(g0 + o) = make_float4(fmaxf(a0,0.f), fmaxf(a1,0.f), fmaxf(a2,0.f), fmaxf(a3,0.f));
}

// ---------------------------------------------------------------------------
// Fused CSR-gather + node update: out = relu(concat(h, sum g0[nbrs], [sum g1[nbrs]]) @ Wn + bn)
// 16-thread group per dst row walks its CSR slice; no atomics anywhere.
// ---------------------------------------------------------------------------
template<int NS>
__global__ __launch_bounds__(256) void fused_update(
    const float* __restrict__ h,
    const int* __restrict__ rp0, const int* __restrict__ pm0, const float* __restrict__ g0,
    const int* __restrict__ rp1, const int* __restrict__ pm1, const float* __restrict__ g1,
    const float* __restrict__ Wn, const float* __restrict__ bn,
    float* __restrict__ out)
{
    __shared__ float Ws[NS * 4096];
    __shared__ float hs[NS][16][65];
    int tid = threadIdx.x;
    for (int t = tid; t < NS * 4096; t += 256) Ws[t] = Wn[t];
    size_t rbase = (size_t)blockIdx.x * 16;
    for (int t = tid; t < 1024; t += 256)
        hs[0][t >> 6][t & 63] = h[rbase * 64 + t];

    int grp = tid >> 4, l = tid & 15;
    int node = (int)rbase + grp;
    {
        float ax = 0.f, ay = 0.f, az = 0.f, aw = 0.f;
        int e0 = rp0[node], e1 = rp0[node + 1];
        for (int e = e0; e < e1; ++e) {
            float4 v = *(const float4*)(g0 + (size_t)pm0[e] * 64 + l * 4);
            ax += v.x; ay += v.y; az += v.z; aw += v.w;
        }
        hs[1][grp][l*4+0] = ax; hs[1][grp][l*4+1] = ay;
        hs[1][grp][l*4+2] = az; hs[1][grp][l*4+3] = aw;
    }
    if constexpr (NS == 3) {
        float ax = 0.f, ay = 0.f, az = 0.f, aw = 0.f;
        int e0 = rp1[node], e1 = rp1[node + 1];
        for (int e = e0; e < e1; ++e) {
            float4 v = *(const float4*)(g1 + (size_t)pm1[e] * 64 + l * 4);
            ax += v.x; ay += v.y; az += v.z; aw += v.w;
        }
        hs[2][grp][l*4+0] = ax; hs[2][grp][l*4+1] = ay;
        hs[2][grp][l*4+2] = az; hs[2][grp][l*4+3] = aw;
    }
    __syncthreads();

    int r  = tid >> 4;
    int c0 = (tid & 15) * 4;
    float a0 = bn[c0], a1 = bn[c0+1], a2 = bn[c0+2], a3 = bn[c0+3];
    for (int s = 0; s < NS; ++s)
        for (int k = 0; k < 64; ++k) {
            float hv = hs[s][r][k];
            float4 w = *(const float4*)&Ws[(s*64 + k)*64 + c0];
            a0 += hv*w.x; a1 += hv*w.y; a2 += hv*w.z; a3 += hv*w.w;
        }
    *(float4*)(out + (rbase + r) * 64 + c0) =
        make_float4(fmaxf(a0,0.f), fmaxf(a1,0.f), fmaxf(a2,0.f), fmaxf(a3,0.f));
}

extern "C" void kernel_launch(void* const* d_in, const int* in_sizes, int n_in,
                              void* d_out, int out_size, void* d_ws, size_t ws_size,
                              hipStream_t stream)
{
    const int*   src_aa = (const int*)d_in[0];
    const int*   dst_aa = (const int*)d_in[1];
    const int*   src_ab = (const int*)d_in[2];
    const int*   dst_ab = (const int*)d_in[3];
    const int*   src_ba = (const int*)d_in[4];
    const int*   dst_ba = (const int*)d_in[5];
    const float* emb_A  = (const float*)d_in[6];
    const float* emb_B  = (const float*)d_in[7];
    const float* W_aa   = (const float*)d_in[8];
    const float* b_aa   = (const float*)d_in[9];
    const float* W_ab   = (const float*)d_in[10];
    const float* b_ab   = (const float*)d_in[11];
    const float* W_ba   = (const float*)d_in[12];
    const float* b_ba   = (const float*)d_in[13];
    const float* Wn_A   = (const float*)d_in[14];
    const float* bn_A   = (const float*)d_in[15];
    const float* Wn_B   = (const float*)d_in[16];
    const float* bn_B   = (const float*)d_in[17];

    // workspace (ints then floats), ~114 MiB total:
    // sv[512] | deg_aa,deg_ba,deg_ab | rp_aa,rp_ba,rp_ab | cur_aa,cur_ba,cur_ab
    // | perm_aa,perm_ab,perm_ba | hA1 | hB1 | gX | gY
    float* ws   = (float*)d_ws;
    float* sv   = ws;
    int*   ib   = (int*)(ws + 512);
    int* deg_aa_p = ib;                 ib += N_A;
    int* deg_ba_p = ib;                 ib += N_A;
    int* deg_ab_p = ib;                 ib += N_B;
    int* rp_aa    = ib;                 ib += N_A + 1;
    int* rp_ba    = ib;                 ib += N_A + 1;
    int* rp_ab    = ib;                 ib += N_B + 1;
    int* cur_aa   = ib;                 ib += N_A;
    int* cur_ba   = ib;                 ib += N_A;
    int* cur_ab   = ib;                 ib += N_B;
    int* perm_aa  = ib;                 ib += E_AA;
    int* perm_ab  = ib;                 ib += E_AB;
    int* perm_ba  = ib;                 ib += E_BA;
    float* hA1 = (float*)ib;
    float* hB1 = hA1 + (size_t)N_A * 64;
    float* gX  = hB1 + (size_t)N_B * 64;   // g_aa, then reused as g_ab
    float* gY  = gX  + (size_t)N_A * 64;   // g_ba

    float* outA = (float*)d_out;
    float* outB = outA + (size_t)N_A * 64;

    hipMemsetAsync(deg_aa_p, 0, (size_t)(2*N_A + N_B) * sizeof(int), stream);

    precompute_vecs<<<1, 64, 0, stream>>>(emb_A, emb_B, W_aa, b_aa, W_ab, b_ab,
                                          W_ba, b_ba, Wn_A, bn_A, Wn_B, bn_B, sv);
    deg_hist<<<(E_AA + 255) / 256, 256, 0, stream>>>(dst_aa, E_AA, deg_aa_p);
    deg_hist<<<(E_AB + 255) / 256, 256, 0, stream>>>(dst_ab, E_AB, deg_ab_p);
    deg_hist<<<(E_BA + 255) / 256, 256, 0, stream>>>(dst_ba, E_BA, deg_ba_p);

    exscan<<<1, 1024, 0, stream>>>(deg_aa_p, N_A, rp_aa, cur_aa);
    exscan<<<1, 1024, 0, stream>>>(deg_ba_p, N_A, rp_ba, cur_ba);
    exscan<<<1, 1024, 0, stream>>>(deg_ab_p, N_B, rp_ab, cur_ab);

    layer0_nodes<<<4096, 256, 0, stream>>>(deg_aa_p, deg_ba_p, deg_ab_p, sv, hA1, hB1);

    fill_perm<<<(E_AA + 255) / 256, 256, 0, stream>>>(src_aa, dst_aa, E_AA, cur_aa, perm_aa);
    fill_perm<<<(E_AB + 255) / 256, 256, 0, stream>>>(src_ab, dst_ab, E_AB, cur_ab, perm_ab);
    fill_perm<<<(E_BA + 255) / 256, 256, 0, stream>>>(src_ba, dst_ba, E_BA, cur_ba, perm_ba);

    // layer-1 per-node edge transforms (layer-1 weight offsets)
    node_transform<<<N_A / 16, 256, 0, stream>>>(hA1, W_aa + 4096, b_aa + 64, gX);  // g_aa
    node_transform<<<N_B / 16, 256, 0, stream>>>(hB1, W_ba + 4096, b_ba + 64, gY);  // g_ba

    // A update: concat [hA1, r_aa(gather gX via aa-CSR), r_ba(gather gY via ba-CSR)]
    fused_update<3><<<N_A / 16, 256, 0, stream>>>(hA1,
        rp_aa, perm_aa, gX, rp_ba, perm_ba, gY,
        Wn_A + 12288, bn_A + 64, outA);

    // gX now dead -> reuse for g_ab
    node_transform<<<N_A / 16, 256, 0, stream>>>(hA1, W_ab + 4096, b_ab + 64, gX);  // g_ab

    // B update: concat [hB1, r_ab(gather gX via ab-CSR)]
    fused_update<2><<<N_B / 16, 256, 0, stream>>>(hB1,
        rp_ab, perm_ab, gX, nullptr, nullptr, nullptr,
        Wn_B + 8192, bn_B + 64, outB);
}

// Round 8
// 743.948 us; speedup vs baseline: 2.8470x; 1.9124x over previous
//
#include <hip/hip_runtime.h>
#include <hip/hip_bf16.h>

#define N_A 100000
#define N_B 100000
#define E_AA 400000
#define E_AB 800000
#define E_BA 800000
#define SCAN_N (2*N_A + N_B)                    // 300000 concatenated degree slots
#define SCAN_BLOCKS ((SCAN_N + 1023) / 1024)    // 293

// ---------------------------------------------------------------------------
// Layer-0 closed form: hA starts as tile(emb_A), so every edge of a type
// carries the same message vector. hA1[i] = relu(cA + deg_aa[i]*u + deg_ba[i]*v)
// sv = [cA, u_aa, v_ba, cB, w_ab] (five 64-vectors)
// ---------------------------------------------------------------------------
__global__ void precompute_vecs(const float* __restrict__ emb_A, const float* __restrict__ emb_B,
    const float* __restrict__ W_aa, const float* __restrict__ b_aa,
    const float* __restrict__ W_ab, const float* __restrict__ b_ab,
    const float* __restrict__ W_ba, const float* __restrict__ b_ba,
    const float* __restrict__ Wn_A, const float* __restrict__ bn_A,
    const float* __restrict__ Wn_B, const float* __restrict__ bn_B,
    float* __restrict__ sv)
{
    __shared__ float ea[64], eb[64], maa[64], mab[64], mba[64];
    int j = threadIdx.x;
    ea[j] = emb_A[j];
    eb[j] = emb_B[j];
    __syncthreads();
    float s_aa = b_aa[j], s_ab = b_ab[j], s_ba = b_ba[j];
    for (int k = 0; k < 64; ++k) {
        s_aa += ea[k] * W_aa[k*64 + j];
        s_ab += ea[k] * W_ab[k*64 + j];
        s_ba += eb[k] * W_ba[k*64 + j];
    }
    maa[j] = fmaxf(s_aa, 0.f);
    mab[j] = fmaxf(s_ab, 0.f);
    mba[j] = fmaxf(s_ba, 0.f);
    __syncthreads();
    float cA = bn_A[j], u = 0.f, v = 0.f, cB = bn_B[j], w = 0.f;
    for (int k = 0; k < 64; ++k) {
        cA += ea[k]  * Wn_A[k*64 + j];
        u  += maa[k] * Wn_A[(64+k)*64 + j];
        v  += mba[k] * Wn_A[(128+k)*64 + j];
        cB += eb[k]  * Wn_B[k*64 + j];
        w  += mab[k] * Wn_B[(64+k)*64 + j];
    }
    sv[j] = cA; sv[64+j] = u; sv[128+j] = v; sv[192+j] = cB; sv[256+j] = w;
}

__global__ void deg_hist(const int* __restrict__ dst, int n, int* __restrict__ deg)
{
    int i = blockIdx.x * blockDim.x + threadIdx.x;
    if (i < n) atomicAdd(deg + dst[i], 1);
}

// ---------------------------------------------------------------------------
// Hierarchical exclusive scan over the 300k concatenated degree array.
// Pass 1: block-local exclusive scan (into scan_tmp) + block totals.
// ---------------------------------------------------------------------------
__global__ __launch_bounds__(1024) void scan_blocks(const int* __restrict__ deg,
                                                    int* __restrict__ scan_tmp,
                                                    int* __restrict__ partials)
{
    __shared__ int ps[1024];
    int tid = threadIdx.x;
    int gid = blockIdx.x * 1024 + tid;
    int v = (gid < SCAN_N) ? deg[gid] : 0;
    ps[tid] = v;
    __syncthreads();
    for (int off = 1; off < 1024; off <<= 1) {
        int t = (tid >= off) ? ps[tid - off] : 0;
        __syncthreads();
        ps[tid] += t;
        __syncthreads();
    }
    if (gid < SCAN_N) scan_tmp[gid] = ps[tid] - v;   // local exclusive
    if (tid == 1023) partials[blockIdx.x] = ps[1023];
}

// Pass 2: exclusive-scan the block totals in place; grand total -> partials[512].
__global__ __launch_bounds__(512) void scan_partials(int* __restrict__ partials)
{
    __shared__ int ps[512];
    int tid = threadIdx.x;
    int v = (tid < SCAN_BLOCKS) ? partials[tid] : 0;
    ps[tid] = v;
    __syncthreads();
    for (int off = 1; off < 512; off <<= 1) {
        int t = (tid >= off) ? ps[tid - off] : 0;
        __syncthreads();
        ps[tid] += t;
        __syncthreads();
    }
    partials[tid] = ps[tid] - v;                     // exclusive
    if (tid == 511) partials[512] = ps[511];         // grand total (= 2M)
}

// Pass 3: add block offsets; emit rp (with end sentinel) and cursor copy.
__global__ __launch_bounds__(1024) void scan_finalize(const int* __restrict__ scan_tmp,
                                                      const int* __restrict__ partials,
                                                      int* __restrict__ rp,
                                                      int* __restrict__ cur)
{
    int gid = blockIdx.x * 1024 + threadIdx.x;
    if (gid < SCAN_N) {
        int v = scan_tmp[gid] + partials[blockIdx.x];
        rp[gid] = v;
        cur[gid] = v;
    }
    if (gid == 0) rp[SCAN_N] = partials[512];
}

// counting-sort fill: perm[] = src indices grouped by dst (global positions)
__global__ void fill_perm(const int* __restrict__ src, const int* __restrict__ dst, int ne,
                          int* __restrict__ cur, int* __restrict__ perm)
{
    int i = blockIdx.x * blockDim.x + threadIdx.x;
    if (i < ne) {
        int p = atomicAdd(cur + dst[i], 1);
        perm[p] = src[i];
    }
}

__global__ void layer0_nodes(const int* __restrict__ deg_aa, const int* __restrict__ deg_ba,
                             const int* __restrict__ deg_ab, const float* __restrict__ sv,
                             float* __restrict__ hA1, float* __restrict__ hB1)
{
    __shared__ float s[320];
    for (int t = threadIdx.x; t < 320; t += blockDim.x)
        s[t] = sv[t];
    __syncthreads();
    int gid = blockIdx.x * blockDim.x + threadIdx.x;
    int total = (N_A + N_B) * 64;
    for (int idx = gid; idx < total; idx += gridDim.x * blockDim.x) {
        int i = idx >> 6, j = idx & 63;
        if (i < N_A) {
            float da = (float)deg_aa[i];
            float db = (float)deg_ba[i];
            hA1[idx] = fmaxf(s[j] + da * s[64+j] + db * s[128+j], 0.f);
        } else {
            int b = i - N_A;
            float dd = (float)deg_ab[b];
            hB1[(size_t)b*64 + j] = fmaxf(s[192+j] + dd * s[256+j], 0.f);
        }
    }
}

// ---------------------------------------------------------------------------
// g = relu(h @ W + b). Block = 256 threads, 16 rows, thread = 4 cols of a row.
// ---------------------------------------------------------------------------
__global__ __launch_bounds__(256) void node_transform(
    const float* __restrict__ h,
    const float* __restrict__ W0, const float* __restrict__ b0,
    float* __restrict__ g0)
{
    __shared__ float Ws[4096];
    __shared__ float hs[16][65];
    int tid = threadIdx.x;
    for (int t = tid; t < 4096; t += 256) Ws[t] = W0[t];
    size_t rbase = (size_t)blockIdx.x * 16;
    for (int t = tid; t < 1024; t += 256)
        hs[t >> 6][t & 63] = h[rbase * 64 + t];
    __syncthreads();
    int r  = tid >> 4;
    int c0 = (tid & 15) * 4;
    float a0 = b0[c0], a1 = b0[c0+1], a2 = b0[c0+2], a3 = b0[c0+3];
    for (int k = 0; k < 64; ++k) {
        float hv = hs[r][k];
        float4 w0 = *(const float4*)&Ws[k*64 + c0];
        a0 += hv*w0.x; a1 += hv*w0.y; a2 += hv*w0.z; a3 += hv*w0.w;
    }
    size_t o = (rbase + r) * 64 + c0;
    *(float4*)(g0 + o) = make_float4(fmaxf(a0,0.f), fmaxf(a1,0.f), fmaxf(a2,0.f), fmaxf(a3,0.f));
}

// ---------------------------------------------------------------------------
// Fused CSR-gather + node update: out = relu(concat(h, sum g0[nbrs], [sum g1[nbrs]]) @ Wn + bn)
// 16-thread group per dst row walks its CSR slice; no atomics anywhere.
// rp slices index into the unified perm buffer (global positions).
// ---------------------------------------------------------------------------
template<int NS>
__global__ __launch_bounds__(256) void fused_update(
    const float* __restrict__ h,
    const int* __restrict__ rp0, const int* __restrict__ pm0, const float* __restrict__ g0,
    const int* __restrict__ rp1, const int* __restrict__ pm1, const float* __restrict__ g1,
    const float* __restrict__ Wn, const float* __restrict__ bn,
    float* __restrict__ out)
{
    __shared__ float Ws[NS * 4096];
    __shared__ float hs[NS][16][65];
    int tid = threadIdx.x;
    for (int t = tid; t < NS * 4096; t += 256) Ws[t] = Wn[t];
    size_t rbase = (size_t)blockIdx.x * 16;
    for (int t = tid; t < 1024; t += 256)
        hs[0][t >> 6][t & 63] = h[rbase * 64 + t];

    int grp = tid >> 4, l = tid & 15;
    int node = (int)rbase + grp;
    {
        float ax = 0.f, ay = 0.f, az = 0.f, aw = 0.f;
        int e0 = rp0[node], e1 = rp0[node + 1];
        for (int e = e0; e < e1; ++e) {
            float4 v = *(const float4*)(g0 + (size_t)pm0[e] * 64 + l * 4);
            ax += v.x; ay += v.y; az += v.z; aw += v.w;
        }
        hs[1][grp][l*4+0] = ax; hs[1][grp][l*4+1] = ay;
        hs[1][grp][l*4+2] = az; hs[1][grp][l*4+3] = aw;
    }
    if constexpr (NS == 3) {
        float ax = 0.f, ay = 0.f, az = 0.f, aw = 0.f;
        int e0 = rp1[node], e1 = rp1[node + 1];
        for (int e = e0; e < e1; ++e) {
            float4 v = *(const float4*)(g1 + (size_t)pm1[e] * 64 + l * 4);
            ax += v.x; ay += v.y; az += v.z; aw += v.w;
        }
        hs[2][grp][l*4+0] = ax; hs[2][grp][l*4+1] = ay;
        hs[2][grp][l*4+2] = az; hs[2][grp][l*4+3] = aw;
    }
    __syncthreads();

    int r  = tid >> 4;
    int c0 = (tid & 15) * 4;
    float a0 = bn[c0], a1 = bn[c0+1], a2 = bn[c0+2], a3 = bn[c0+3];
    for (int s = 0; s < NS; ++s)
        for (int k = 0; k < 64; ++k) {
            float hv = hs[s][r][k];
            float4 w = *(const float4*)&Ws[(s*64 + k)*64 + c0];
            a0 += hv*w.x; a1 += hv*w.y; a2 += hv*w.z; a3 += hv*w.w;
        }
    *(float4*)(out + (rbase + r) * 64 + c0) =
        make_float4(fmaxf(a0,0.f), fmaxf(a1,0.f), fmaxf(a2,0.f), fmaxf(a3,0.f));
}

extern "C" void kernel_launch(void* const* d_in, const int* in_sizes, int n_in,
                              void* d_out, int out_size, void* d_ws, size_t ws_size,
                              hipStream_t stream)
{
    const int*   src_aa = (const int*)d_in[0];
    const int*   dst_aa = (const int*)d_in[1];
    const int*   src_ab = (const int*)d_in[2];
    const int*   dst_ab = (const int*)d_in[3];
    const int*   src_ba = (const int*)d_in[4];
    const int*   dst_ba = (const int*)d_in[5];
    const float* emb_A  = (const float*)d_in[6];
    const float* emb_B  = (const float*)d_in[7];
    const float* W_aa   = (const float*)d_in[8];
    const float* b_aa   = (const float*)d_in[9];
    const float* W_ab   = (const float*)d_in[10];
    const float* b_ab   = (const float*)d_in[11];
    const float* W_ba   = (const float*)d_in[12];
    const float* b_ba   = (const float*)d_in[13];
    const float* Wn_A   = (const float*)d_in[14];
    const float* bn_A   = (const float*)d_in[15];
    const float* Wn_B   = (const float*)d_in[16];
    const float* bn_B   = (const float*)d_in[17];

    // workspace (~116 MiB):
    // sv[512] | deg_all[300k] | scan_tmp[300k] | rp_all[300k+1] | cur_all[300k]
    // | partials[640] | perm_all[2M] | hA1 | hB1 | gX | gY
    // deg_all sections: aa @0, ba @N_A, ab @2*N_A (concatenated -> one scan,
    // global perm positions fall out automatically).
    float* ws   = (float*)d_ws;
    float* sv   = ws;
    int*   ib   = (int*)(ws + 512);
    int* deg_all  = ib;                 ib += SCAN_N;
    int* scan_tmp = ib;                 ib += SCAN_N;
    int* rp_all   = ib;                 ib += SCAN_N + 1;
    int* cur_all  = ib;                 ib += SCAN_N;
    int* partials = ib;                 ib += 640;
    int* perm_all = ib;                 ib += E_AA + E_BA + E_AB;
    float* hA1 = (float*)ib;
    float* hB1 = hA1 + (size_t)N_A * 64;
    float* gX  = hB1 + (size_t)N_B * 64;   // g_aa, then reused as g_ab
    float* gY  = gX  + (size_t)N_A * 64;   // g_ba

    float* outA = (float*)d_out;
    float* outB = outA + (size_t)N_A * 64;

    hipMemsetAsync(deg_all, 0, (size_t)SCAN_N * sizeof(int), stream);

    precompute_vecs<<<1, 64, 0, stream>>>(emb_A, emb_B, W_aa, b_aa, W_ab, b_ab,
                                          W_ba, b_ba, Wn_A, bn_A, Wn_B, bn_B, sv);
    deg_hist<<<(E_AA + 255) / 256, 256, 0, stream>>>(dst_aa, E_AA, deg_all);            // aa section
    deg_hist<<<(E_BA + 255) / 256, 256, 0, stream>>>(dst_ba, E_BA, deg_all + N_A);      // ba section
    deg_hist<<<(E_AB + 255) / 256, 256, 0, stream>>>(dst_ab, E_AB, deg_all + 2*N_A);    // ab section

    scan_blocks  <<<SCAN_BLOCKS, 1024, 0, stream>>>(deg_all, scan_tmp, partials);
    scan_partials<<<1, 512, 0, stream>>>(partials);
    scan_finalize<<<SCAN_BLOCKS, 1024, 0, stream>>>(scan_tmp, partials, rp_all, cur_all);

    layer0_nodes<<<4096, 256, 0, stream>>>(deg_all, deg_all + N_A, deg_all + 2*N_A,
                                           sv, hA1, hB1);

    fill_perm<<<(E_AA + 255) / 256, 256, 0, stream>>>(src_aa, dst_aa, E_AA, cur_all,         perm_all);
    fill_perm<<<(E_BA + 255) / 256, 256, 0, stream>>>(src_ba, dst_ba, E_BA, cur_all + N_A,   perm_all);
    fill_perm<<<(E_AB + 255) / 256, 256, 0, stream>>>(src_ab, dst_ab, E_AB, cur_all + 2*N_A, perm_all);

    // layer-1 per-node edge transforms (layer-1 weight offsets)
    node_transform<<<N_A / 16, 256, 0, stream>>>(hA1, W_aa + 4096, b_aa + 64, gX);  // g_aa
    node_transform<<<N_B / 16, 256, 0, stream>>>(hB1, W_ba + 4096, b_ba + 64, gY);  // g_ba

    // A update: concat [hA1, r_aa(gather gX via aa-CSR), r_ba(gather gY via ba-CSR)]
    fused_update<3><<<N_A / 16, 256, 0, stream>>>(hA1,
        rp_all, perm_all, gX, rp_all + N_A, perm_all, gY,
        Wn_A + 12288, bn_A + 64, outA);

    // gX now dead -> reuse for g_ab
    node_transform<<<N_A / 16, 256, 0, stream>>>(hA1, W_ab + 4096, b_ab + 64, gX);  // g_ab

    // B update: concat [hB1, r_ab(gather gX via ab-CSR)]
    fused_update<2><<<N_B / 16, 256, 0, stream>>>(hB1,
        rp_all + 2*N_A, perm_all, gX, nullptr, nullptr, nullptr,
        Wn_B + 8192, bn_B + 64, outB);
}

// Round 9
// 659.016 us; speedup vs baseline: 3.2140x; 1.1289x over previous
//
#include <hip/hip_runtime.h>
#include <hip/hip_bf16.h>

#define N_A 100000
#define N_B 100000
#define E_AA 400000
#define E_AB 800000
#define E_BA 800000
#define SCAN_N (2*N_A + N_B)                    // 300000 concatenated degree slots
#define SCAN_BLOCKS ((SCAN_N + 1023) / 1024)    // 293

// ---------------------------------------------------------------------------
// Layer-0 closed form (hA0/hB0 are single tiled rows):
// hA1[i] = relu(cA + deg_aa[i]*u + deg_ba[i]*v), hB1[i] = relu(cB + deg_ab[i]*w)
// sv = [cA, u_aa, v_ba, cB, w_ab]
// ---------------------------------------------------------------------------
__global__ void precompute_vecs(const float* __restrict__ emb_A, const float* __restrict__ emb_B,
    const float* __restrict__ W_aa, const float* __restrict__ b_aa,
    const float* __restrict__ W_ab, const float* __restrict__ b_ab,
    const float* __restrict__ W_ba, const float* __restrict__ b_ba,
    const float* __restrict__ Wn_A, const float* __restrict__ bn_A,
    const float* __restrict__ Wn_B, const float* __restrict__ bn_B,
    float* __restrict__ sv)
{
    __shared__ float ea[64], eb[64], maa[64], mab[64], mba[64];
    int j = threadIdx.x;
    ea[j] = emb_A[j];
    eb[j] = emb_B[j];
    __syncthreads();
    float s_aa = b_aa[j], s_ab = b_ab[j], s_ba = b_ba[j];
    for (int k = 0; k < 64; ++k) {
        s_aa += ea[k] * W_aa[k*64 + j];
        s_ab += ea[k] * W_ab[k*64 + j];
        s_ba += eb[k] * W_ba[k*64 + j];
    }
    maa[j] = fmaxf(s_aa, 0.f);
    mab[j] = fmaxf(s_ab, 0.f);
    mba[j] = fmaxf(s_ba, 0.f);
    __syncthreads();
    float cA = bn_A[j], u = 0.f, v = 0.f, cB = bn_B[j], w = 0.f;
    for (int k = 0; k < 64; ++k) {
        cA += ea[k]  * Wn_A[k*64 + j];
        u  += maa[k] * Wn_A[(64+k)*64 + j];
        v  += mba[k] * Wn_A[(128+k)*64 + j];
        cB += eb[k]  * Wn_B[k*64 + j];
        w  += mab[k] * Wn_B[(64+k)*64 + j];
    }
    sv[j] = cA; sv[64+j] = u; sv[128+j] = v; sv[192+j] = cB; sv[256+j] = w;
}

__global__ void deg_hist(const int* __restrict__ dst, int n, int* __restrict__ deg)
{
    int i = blockIdx.x * blockDim.x + threadIdx.x;
    if (i < n) atomicAdd(deg + dst[i], 1);
}

// ---------------------------------------------------------------------------
// Hierarchical exclusive scan over the 300k concatenated degree array.
// ---------------------------------------------------------------------------
__global__ __launch_bounds__(1024) void scan_blocks(const int* __restrict__ deg,
                                                    int* __restrict__ scan_tmp,
                                                    int* __restrict__ partials)
{
    __shared__ int ps[1024];
    int tid = threadIdx.x;
    int gid = blockIdx.x * 1024 + tid;
    int v = (gid < SCAN_N) ? deg[gid] : 0;
    ps[tid] = v;
    __syncthreads();
    for (int off = 1; off < 1024; off <<= 1) {
        int t = (tid >= off) ? ps[tid - off] : 0;
        __syncthreads();
        ps[tid] += t;
        __syncthreads();
    }
    if (gid < SCAN_N) scan_tmp[gid] = ps[tid] - v;   // local exclusive
    if (tid == 1023) partials[blockIdx.x] = ps[1023];
}

__global__ __launch_bounds__(512) void scan_partials(int* __restrict__ partials)
{
    __shared__ int ps[512];
    int tid = threadIdx.x;
    int v = (tid < SCAN_BLOCKS) ? partials[tid] : 0;
    ps[tid] = v;
    __syncthreads();
    for (int off = 1; off < 512; off <<= 1) {
        int t = (tid >= off) ? ps[tid - off] : 0;
        __syncthreads();
        ps[tid] += t;
        __syncthreads();
    }
    partials[tid] = ps[tid] - v;                     // exclusive
    if (tid == 511) partials[512] = ps[511];         // grand total
}

__global__ __launch_bounds__(1024) void scan_finalize(const int* __restrict__ scan_tmp,
                                                      const int* __restrict__ partials,
                                                      int* __restrict__ rp,
                                                      int* __restrict__ cur)
{
    int gid = blockIdx.x * 1024 + threadIdx.x;
    if (gid < SCAN_N) {
        int v = scan_tmp[gid] + partials[blockIdx.x];
        rp[gid] = v;
        cur[gid] = v;
    }
    if (gid == 0) rp[SCAN_N] = partials[512];
}

// counting-sort fill: perm[] = src indices grouped by dst (global positions)
__global__ void fill_perm(const int* __restrict__ src, const int* __restrict__ dst, int ne,
                          int* __restrict__ cur, int* __restrict__ perm)
{
    int i = blockIdx.x * blockDim.x + threadIdx.x;
    if (i < ne) {
        int p = atomicAdd(cur + dst[i], 1);
        perm[p] = src[i];
    }
}

__global__ void layer0_nodes(const int* __restrict__ deg_aa, const int* __restrict__ deg_ba,
                             const int* __restrict__ deg_ab, const float* __restrict__ sv,
                             float* __restrict__ hA1, float* __restrict__ hB1)
{
    __shared__ float s[320];
    for (int t = threadIdx.x; t < 320; t += blockDim.x)
        s[t] = sv[t];
    __syncthreads();
    int gid = blockIdx.x * blockDim.x + threadIdx.x;
    int total = (N_A + N_B) * 64;
    for (int idx = gid; idx < total; idx += gridDim.x * blockDim.x) {
        int i = idx >> 6, j = idx & 63;
        if (i < N_A) {
            float da = (float)deg_aa[i];
            float db = (float)deg_ba[i];
            hA1[idx] = fmaxf(s[j] + da * s[64+j] + db * s[128+j], 0.f);
        } else {
            int b = i - N_A;
            float dd = (float)deg_ab[b];
            hB1[(size_t)b*64 + j] = fmaxf(s[192+j] + dd * s[256+j], 0.f);
        }
    }
}

// ---------------------------------------------------------------------------
// g = relu(h @ W + b). Block = 256 threads, 16 rows, thread = 4 cols of a row.
// ---------------------------------------------------------------------------
__global__ __launch_bounds__(256) void node_transform(
    const float* __restrict__ h,
    const float* __restrict__ W0, const float* __restrict__ b0,
    float* __restrict__ g0)
{
    __shared__ float Ws[4096];
    __shared__ float hs[16][65];
    int tid = threadIdx.x;
    for (int t = tid; t < 4096; t += 256) Ws[t] = W0[t];
    size_t rbase = (size_t)blockIdx.x * 16;
    for (int t = tid; t < 1024; t += 256)
        hs[t >> 6][t & 63] = h[rbase * 64 + t];
    __syncthreads();
    int r  = tid >> 4;
    int c0 = (tid & 15) * 4;
    float a0 = b0[c0], a1 = b0[c0+1], a2 = b0[c0+2], a3 = b0[c0+3];
    for (int k = 0; k < 64; ++k) {
        float hv = hs[r][k];
        float4 w0 = *(const float4*)&Ws[k*64 + c0];
        a0 += hv*w0.x; a1 += hv*w0.y; a2 += hv*w0.z; a3 += hv*w0.w;
    }
    size_t o = (rbase + r) * 64 + c0;
    *(float4*)(g0 + o) = make_float4(fmaxf(a0,0.f), fmaxf(a1,0.f), fmaxf(a2,0.f), fmaxf(a3,0.f));
}

// ---------------------------------------------------------------------------
// Standalone CSR gather: r[node] = sum over nbrs of g[src]. LDS-free, low
// VGPR -> max occupancy; 16 lanes/node, float4/lane, e-loop unrolled x2
// for memory-level parallelism.
// ---------------------------------------------------------------------------
__global__ __launch_bounds__(256) void gather_csr(
    const int* __restrict__ rp, const int* __restrict__ pm,
    const float* __restrict__ g, float* __restrict__ r, int n)
{
    int gid = blockIdx.x * 256 + threadIdx.x;
    int node = gid >> 4;
    int l = gid & 15;
    if (node >= n) return;
    int e0 = rp[node], e1 = rp[node + 1];
    float ax = 0.f, ay = 0.f, az = 0.f, aw = 0.f;
    float bx = 0.f, by = 0.f, bz = 0.f, bw = 0.f;
    int e = e0;
    for (; e + 1 < e1; e += 2) {
        int s0 = pm[e], s1 = pm[e + 1];
        float4 v0 = *(const float4*)(g + (size_t)s0 * 64 + l * 4);
        float4 v1 = *(const float4*)(g + (size_t)s1 * 64 + l * 4);
        ax += v0.x; ay += v0.y; az += v0.z; aw += v0.w;
        bx += v1.x; by += v1.y; bz += v1.z; bw += v1.w;
    }
    if (e < e1) {
        float4 v = *(const float4*)(g + (size_t)pm[e] * 64 + l * 4);
        ax += v.x; ay += v.y; az += v.z; aw += v.w;
    }
    *(float4*)(r + (size_t)node * 64 + l * 4) =
        make_float4(ax + bx, ay + by, az + bz, aw + bw);
}

// ---------------------------------------------------------------------------
// out = relu(concat(h, r0, [r1]) @ Wn + bn). r0/r1 may alias out (each block
// reads only its own 16 rows into LDS before writing them back).
// ---------------------------------------------------------------------------
template<int NS>
__global__ __launch_bounds__(256) void node_update(
    const float* __restrict__ h,
    const float* r0,                  // no restrict: may alias out
    const float* r1,                  // no restrict: may alias out
    const float* __restrict__ Wn, const float* __restrict__ bn,
    float* out)
{
    __shared__ float Ws[NS * 4096];
    __shared__ float hs[NS][16][65];
    int tid = threadIdx.x;
    for (int t = tid; t < NS * 4096; t += 256) Ws[t] = Wn[t];
    size_t rbase = (size_t)blockIdx.x * 16;
    for (int t = tid; t < 1024; t += 256) {
        int rr = t >> 6, k = t & 63;
        size_t gi = rbase * 64 + t;
        hs[0][rr][k] = h[gi];
        hs[1][rr][k] = r0[gi];
        if constexpr (NS == 3) hs[2][rr][k] = r1[gi];
    }
    __syncthreads();
    int r  = tid >> 4;
    int c0 = (tid & 15) * 4;
    float a0 = bn[c0], a1 = bn[c0+1], a2 = bn[c0+2], a3 = bn[c0+3];
    for (int s = 0; s < NS; ++s)
        for (int k = 0; k < 64; ++k) {
            float hv = hs[s][r][k];
            float4 w = *(const float4*)&Ws[(s*64 + k)*64 + c0];
            a0 += hv*w.x; a1 += hv*w.y; a2 += hv*w.z; a3 += hv*w.w;
        }
    *(float4*)(out + (rbase + r) * 64 + c0) =
        make_float4(fmaxf(a0,0.f), fmaxf(a1,0.f), fmaxf(a2,0.f), fmaxf(a3,0.f));
}

extern "C" void kernel_launch(void* const* d_in, const int* in_sizes, int n_in,
                              void* d_out, int out_size, void* d_ws, size_t ws_size,
                              hipStream_t stream)
{
    const int*   src_aa = (const int*)d_in[0];
    const int*   dst_aa = (const int*)d_in[1];
    const int*   src_ab = (const int*)d_in[2];
    const int*   dst_ab = (const int*)d_in[3];
    const int*   src_ba = (const int*)d_in[4];
    const int*   dst_ba = (const int*)d_in[5];
    const float* emb_A  = (const float*)d_in[6];
    const float* emb_B  = (const float*)d_in[7];
    const float* W_aa   = (const float*)d_in[8];
    const float* b_aa   = (const float*)d_in[9];
    const float* W_ab   = (const float*)d_in[10];
    const float* b_ab   = (const float*)d_in[11];
    const float* W_ba   = (const float*)d_in[12];
    const float* b_ba   = (const float*)d_in[13];
    const float* Wn_A   = (const float*)d_in[14];
    const float* bn_A   = (const float*)d_in[15];
    const float* Wn_B   = (const float*)d_in[16];
    const float* bn_B   = (const float*)d_in[17];

    // workspace (~116 MiB):
    // sv[512] | deg_all[300k] | scan_tmp[300k] | rp_all[300k+1] | cur_all[300k]
    // | partials[640] | perm_all[2M] | hA1 | hB1 | gX | gY
    // r-buffer overlays: r_aa -> outA, r_ba -> outB, r_ab -> gY (after free).
    float* ws   = (float*)d_ws;
    float* sv   = ws;
    int*   ib   = (int*)(ws + 512);
    int* deg_all  = ib;                 ib += SCAN_N;
    int* scan_tmp = ib;                 ib += SCAN_N;
    int* rp_all   = ib;                 ib += SCAN_N + 1;
    int* cur_all  = ib;                 ib += SCAN_N;
    int* partials = ib;                 ib += 640;
    int* perm_all = ib;                 ib += E_AA + E_BA + E_AB;
    float* hA1 = (float*)ib;
    float* hB1 = hA1 + (size_t)N_A * 64;
    float* gX  = hB1 + (size_t)N_B * 64;   // g_aa, then reused as g_ab
    float* gY  = gX  + (size_t)N_A * 64;   // g_ba, then reused as r_ab

    float* outA = (float*)d_out;           // doubles as r_aa
    float* outB = outA + (size_t)N_A * 64; // doubles as r_ba (until update B)

    hipMemsetAsync(deg_all, 0, (size_t)SCAN_N * sizeof(int), stream);

    precompute_vecs<<<1, 64, 0, stream>>>(emb_A, emb_B, W_aa, b_aa, W_ab, b_ab,
                                          W_ba, b_ba, Wn_A, bn_A, Wn_B, bn_B, sv);
    deg_hist<<<(E_AA + 255) / 256, 256, 0, stream>>>(dst_aa, E_AA, deg_all);            // aa
    deg_hist<<<(E_BA + 255) / 256, 256, 0, stream>>>(dst_ba, E_BA, deg_all + N_A);      // ba
    deg_hist<<<(E_AB + 255) / 256, 256, 0, stream>>>(dst_ab, E_AB, deg_all + 2*N_A);    // ab

    scan_blocks  <<<SCAN_BLOCKS, 1024, 0, stream>>>(deg_all, scan_tmp, partials);
    scan_partials<<<1, 512, 0, stream>>>(partials);
    scan_finalize<<<SCAN_BLOCKS, 1024, 0, stream>>>(scan_tmp, partials, rp_all, cur_all);

    layer0_nodes<<<4096, 256, 0, stream>>>(deg_all, deg_all + N_A, deg_all + 2*N_A,
                                           sv, hA1, hB1);

    fill_perm<<<(E_AA + 255) / 256, 256, 0, stream>>>(src_aa, dst_aa, E_AA, cur_all,         perm_all);
    fill_perm<<<(E_BA + 255) / 256, 256, 0, stream>>>(src_ba, dst_ba, E_BA, cur_all + N_A,   perm_all);
    fill_perm<<<(E_AB + 255) / 256, 256, 0, stream>>>(src_ab, dst_ab, E_AB, cur_all + 2*N_A, perm_all);

    // layer-1 per-node edge transforms (layer-1 weight offsets)
    node_transform<<<N_A / 16, 256, 0, stream>>>(hA1, W_aa + 4096, b_aa + 64, gX);  // g_aa
    node_transform<<<N_B / 16, 256, 0, stream>>>(hB1, W_ba + 4096, b_ba + 64, gY);  // g_ba

    // atomic-free CSR gathers (LDS-free, max occupancy)
    gather_csr<<<(N_A * 16) / 256, 256, 0, stream>>>(rp_all,         perm_all, gX, outA, N_A); // r_aa
    gather_csr<<<(N_A * 16) / 256, 256, 0, stream>>>(rp_all + N_A,   perm_all, gY, outB, N_A); // r_ba

    // A update: concat [hA1, r_aa(outA), r_ba(outB)] -> outA
    node_update<3><<<N_A / 16, 256, 0, stream>>>(hA1, outA, outB,
                                                 Wn_A + 12288, bn_A + 64, outA);

    // gX dead -> g_ab; gY dead -> r_ab
    node_transform<<<N_A / 16, 256, 0, stream>>>(hA1, W_ab + 4096, b_ab + 64, gX);
    gather_csr<<<(N_B * 16) / 256, 256, 0, stream>>>(rp_all + 2*N_A, perm_all, gX, gY, N_B);   // r_ab

    // B update: concat [hB1, r_ab(gY)] -> outB
    node_update<2><<<N_B / 16, 256, 0, stream>>>(hB1, gY, nullptr,
                                                 Wn_B + 8192, bn_B + 64, outB);
}